// Round 1
// baseline (232.055 us; speedup 1.0000x reference)
//
#include <hip/hip_runtime.h>

#define DIM 256
#define HALF 128

// One wave (64 lanes) per output row. Lane j computes dims [4j, 4j+4):
//   i0 = 2j, i1 = 2j+1
//   out = { sin(x*f_i0), cos(x*f_i0), sin(x*f_i1), cos(x*f_i1) }
// inv_freq_i = 10000^(-2i/256) = exp2(-i * log2(10000)/128), computed ONCE
// per lane before the row loop (host-free, but amortized over all rows).
// v_sin_f32 / v_cos_f32 take REVOLUTIONS; we scale by 1/(2pi) and fract-reduce.
__global__ __launch_bounds__(256) void SinusoidalEmbedding_kernel(
    const float* __restrict__ x, float* __restrict__ out, int n) {
    const int lane = threadIdx.x & 63;
    const int waveId = threadIdx.x >> 6;
    const int wavesPerBlock = blockDim.x >> 6;
    int row = blockIdx.x * wavesPerBlock + waveId;
    const int rowStride = gridDim.x * wavesPerBlock;

    // log2(10000) / 128
    const float k = 0.103810252965228506f;
    const float i0 = (float)(2 * lane);
    const float f0 = exp2f(-i0 * k);          // v_exp_f32
    const float f1 = exp2f(-(i0 + 1.0f) * k);
    const float INV2PI = 0.15915494309189535f;

    for (; row < n; row += rowStride) {
        const float xv = x[row];  // wave-uniform broadcast load
        float t0 = xv * f0 * INV2PI;  // revolutions
        float t1 = xv * f1 * INV2PI;
        t0 -= floorf(t0);  // reduce to [0,1) for v_sin/v_cos
        t1 -= floorf(t1);
        float4 o;
        o.x = __builtin_amdgcn_sinf(t0);  // sin(2*pi*t0)
        o.y = __builtin_amdgcn_cosf(t0);
        o.z = __builtin_amdgcn_sinf(t1);
        o.w = __builtin_amdgcn_cosf(t1);
        *reinterpret_cast<float4*>(out + (size_t)row * DIM + lane * 4) = o;
    }
}

extern "C" void kernel_launch(void* const* d_in, const int* in_sizes, int n_in,
                              void* d_out, int out_size, void* d_ws, size_t ws_size,
                              hipStream_t stream) {
    const float* x = (const float*)d_in[0];
    float* out = (float*)d_out;
    const int n = in_sizes[0];  // 1048576 rows

    const int block = 256;              // 4 waves/block
    const int grid = 2048;              // 8 blocks/CU, grid-stride over rows
    SinusoidalEmbedding_kernel<<<grid, block, 0, stream>>>(x, out, n);
}

// Round 2
// 193.726 us; speedup vs baseline: 1.1979x; 1.1979x over previous
//
#include <hip/hip_runtime.h>

#define DIM 256

// One wave = 64 rows per batch. One coalesced load x[base+lane] fetches 64
// rows' timesteps at once (full MLP, 1 load per 64 KiB of output); each row's
// value is then broadcast in-register via __shfl (v_readlane on unrolled
// constant index). Lane j writes dims [4j, 4j+4) of each row: one float4 =
// 1 KiB contiguous per wave per row (ideal store coalescing, full 64B lines).
// v_sin/v_cos take REVOLUTIONS: premultiply freqs by 1/(2pi), fract-reduce.
__global__ __launch_bounds__(256) void SinusoidalEmbedding_kernel(
    const float* __restrict__ x, float* __restrict__ out, int n) {
    const int lane = threadIdx.x & 63;
    const int wid = blockIdx.x * (blockDim.x >> 6) + (threadIdx.x >> 6);
    const int nw = gridDim.x * (blockDim.x >> 6);

    const float k = 0.103810252965228506f;      // log2(10000)/128
    const float INV2PI = 0.15915494309189535f;  // radians -> revolutions
    const float i0 = (float)(2 * lane);
    const float g0 = exp2f(-i0 * k) * INV2PI;          // lane's freq 2j
    const float g1 = exp2f(-(i0 + 1.0f) * k) * INV2PI; // lane's freq 2j+1

    for (int base = wid * 64; base < n; base += nw * 64) {
        const int nb = min(64, n - base);
        const float xv = (lane < nb) ? x[base + lane] : 0.0f;  // 64 rows, 1 load
        float* o = out + (size_t)base * DIM + lane * 4;

        if (nb == 64) {
            #pragma unroll 8
            for (int r = 0; r < 64; ++r) {
                const float xr = __shfl(xv, r);  // broadcast row r's timestep
                float t0 = xr * g0; t0 -= floorf(t0);  // v_fract
                float t1 = xr * g1; t1 -= floorf(t1);
                float4 v;
                v.x = __builtin_amdgcn_sinf(t0);  // sin(2*pi*t0)
                v.y = __builtin_amdgcn_cosf(t0);
                v.z = __builtin_amdgcn_sinf(t1);
                v.w = __builtin_amdgcn_cosf(t1);
                *reinterpret_cast<float4*>(o + (size_t)r * DIM) = v;
            }
        } else {
            for (int r = 0; r < nb; ++r) {  // tail (n % 64 != 0) — not hit here
                const float xr = __shfl(xv, r);
                float t0 = xr * g0; t0 -= floorf(t0);
                float t1 = xr * g1; t1 -= floorf(t1);
                float4 v;
                v.x = __builtin_amdgcn_sinf(t0);
                v.y = __builtin_amdgcn_cosf(t0);
                v.z = __builtin_amdgcn_sinf(t1);
                v.w = __builtin_amdgcn_cosf(t1);
                *reinterpret_cast<float4*>(o + (size_t)r * DIM) = v;
            }
        }
    }
}

extern "C" void kernel_launch(void* const* d_in, const int* in_sizes, int n_in,
                              void* d_out, int out_size, void* d_ws, size_t ws_size,
                              hipStream_t stream) {
    const float* x = (const float*)d_in[0];
    float* out = (float*)d_out;
    const int n = in_sizes[0];  // 1048576 rows

    const int block = 256;  // 4 waves/block
    const int grid = 2048;  // 8192 waves -> exactly 2 batches of 64 rows each
    SinusoidalEmbedding_kernel<<<grid, block, 0, stream>>>(x, out, n);
}